// Round 1
// baseline (1820.976 us; speedup 1.0000x reference)
//
#include <hip/hip_runtime.h>
#include <hip/hip_bf16.h>
#include <math.h>

// ---------------------------------------------------------------------------
// MultiScaleGNN: 3x GAT (single head) -> BiLSTM JK attention -> linear out
// All f32. N = in_sizes[0]/128 nodes, E = in_sizes[1]/2 edges (+N self loops).
// ---------------------------------------------------------------------------

__device__ __forceinline__ float sigmoid_f(float x) {
    return 1.0f / (1.0f + __expf(-x));
}
__device__ __forceinline__ float tanh_f(float x) {
    return 2.0f / (1.0f + __expf(-2.0f * x)) - 1.0f;
}

__device__ __forceinline__ void atomicMaxF(float* addr, float v) {
    if (v >= 0.0f)
        atomicMax(reinterpret_cast<int*>(addr), __float_as_int(v));
    else
        atomicMin(reinterpret_cast<unsigned int*>(addr), __float_as_uint(v));
}

// ---- GAT: h = x @ W^T ; al = h @ asrc ; ar = h @ adst  (one wave per node) --
template<int K>
__global__ __launch_bounds__(256) void lin_kernel(
    const float* __restrict__ x, const float* __restrict__ W,
    const float* __restrict__ asrc, const float* __restrict__ adst,
    float* __restrict__ h, float* __restrict__ al, float* __restrict__ ar, int N)
{
    __shared__ float Wl[64][K + 1];           // +1 pad: kill bank conflicts
    for (int i = threadIdx.x; i < 64 * K; i += 256)
        Wl[i / K][i % K] = W[i];
    __syncthreads();

    int lane = threadIdx.x & 63;
    float as = asrc[lane], ad = adst[lane];
    int wid = (blockIdx.x * 256 + threadIdx.x) >> 6;
    int nw  = (gridDim.x * 256) >> 6;
    for (int n = wid; n < N; n += nw) {
        const float* xr = x + (size_t)n * K;
        float acc = 0.0f;
        #pragma unroll
        for (int k = 0; k < K; k += 4) {
            float4 xv = *reinterpret_cast<const float4*>(xr + k);
            acc += xv.x * Wl[lane][k]     + xv.y * Wl[lane][k + 1]
                 + xv.z * Wl[lane][k + 2] + xv.w * Wl[lane][k + 3];
        }
        h[(size_t)n * 64 + lane] = acc;
        float pa = acc * as, pr = acc * ad;
        #pragma unroll
        for (int off = 32; off > 0; off >>= 1) {
            pa += __shfl_down(pa, off);
            pr += __shfl_down(pr, off);
        }
        if (lane == 0) { al[n] = pa; ar[n] = pr; }
    }
}

// ---- per-layer init: m=-inf, den=0, acc=0 ---------------------------------
__global__ void init_layer(float* __restrict__ m, float* __restrict__ den,
                           float* __restrict__ acc, int N)
{
    int i = blockIdx.x * blockDim.x + threadIdx.x;
    if (i < N * 64) acc[i] = 0.0f;
    if (i < N) { m[i] = -INFINITY; den[i] = 0.0f; }
}

// ---- edge pass 1: e = leaky_relu(al[s]+ar[d]); segment max into m ---------
__global__ __launch_bounds__(256) void edge1(
    const int* __restrict__ src, const int* __restrict__ dst,
    const float* __restrict__ al, const float* __restrict__ ar,
    float* __restrict__ e, float* __restrict__ m, int E, int N)
{
    int Et = E + N;
    for (int i = blockIdx.x * blockDim.x + threadIdx.x; i < Et;
         i += gridDim.x * blockDim.x) {
        int s = (i < E) ? src[i] : (i - E);
        int d = (i < E) ? dst[i] : (i - E);
        float v = al[s] + ar[d];
        v = (v >= 0.0f) ? v : 0.2f * v;
        e[i] = v;
        atomicMaxF(&m[d], v);
    }
}

// ---- edge pass 2 (one wave/edge): den += exp(e-m); acc += exp(e-m)*h[src] -
__global__ __launch_bounds__(256) void edge2(
    const int* __restrict__ src, const int* __restrict__ dst,
    const float* __restrict__ e, const float* __restrict__ m,
    const float* __restrict__ h, float* __restrict__ den,
    float* __restrict__ acc, int E, int N)
{
    int Et = E + N;
    int lane = threadIdx.x & 63;
    int wid = (blockIdx.x * 256 + threadIdx.x) >> 6;
    int nw  = (gridDim.x * 256) >> 6;
    for (int i = wid; i < Et; i += nw) {
        int s = (i < E) ? src[i] : (i - E);
        int d = (i < E) ? dst[i] : (i - E);
        float ex = __expf(e[i] - m[d]);
        if (lane == 0) atomicAdd(&den[d], ex);
        atomicAdd(&acc[(size_t)d * 64 + lane], ex * h[(size_t)s * 64 + lane]);
    }
}

// ---- finalize layer: seq_l = relu(acc/den + b) ----------------------------
__global__ void finalize_kernel(const float* __restrict__ acc,
                                const float* __restrict__ den,
                                const float* __restrict__ b,
                                float* __restrict__ outseq, int N)
{
    int i = blockIdx.x * blockDim.x + threadIdx.x;
    if (i >= N * 64) return;
    int n = i >> 6, j = i & 63;
    float v = acc[i] / den[n] + b[j];
    outseq[i] = fmaxf(v, 0.0f);
}

// ---- LSTM weight pre-transpose into wave-friendly layout ------------------
// Per dir: WihT[(k*4+t)*96+uu] = Wih[(t+4*uu)*64+k]          (64*384 floats)
//          WhhT[(k*4+t)*96+uu] = Whh[(t+4*uu)*96+k]          (96*384 floats)
//          bsum[t*96+uu]       = bih[t+4*uu] + bhh[t+4*uu]   (384 floats)
// dir stride = 24576 + 36864 + 384 = 61824
__global__ void prep_lstm(
    const float* __restrict__ WihF, const float* __restrict__ WhhF,
    const float* __restrict__ bihF, const float* __restrict__ bhhF,
    const float* __restrict__ WihB, const float* __restrict__ WhhB,
    const float* __restrict__ bihB, const float* __restrict__ bhhB,
    float* __restrict__ WT)
{
    int tid = blockIdx.x * blockDim.x + threadIdx.x;
    if (tid >= 2 * 61824) return;
    int dir = tid / 61824;
    int r = tid % 61824;
    const float* Wih = dir ? WihB : WihF;
    const float* Whh = dir ? WhhB : WhhF;
    const float* bih = dir ? bihB : bihF;
    const float* bhh = dir ? bhhB : bhhF;
    float v;
    if (r < 24576) {
        int k = r / 384, t = (r % 384) / 96, uu = r % 96;
        v = Wih[(t + 4 * uu) * 64 + k];
    } else if (r < 61440) {
        int q = r - 24576;
        int k = q / 384, t = (q % 384) / 96, uu = q % 96;
        v = Whh[(t + 4 * uu) * 96 + k];
    } else {
        int q = r - 61440;
        int t = q / 96, uu = q % 96;
        int u = t + 4 * uu;
        v = bih[u] + bhh[u];
    }
    WT[tid] = v;
}

// ---- fused BiLSTM + JK attention + output projection ----------------------
// Block = 256 threads = 4 waves, 64 nodes. lane tx = node-in-tile,
// wave ty owns gate indices j == ty (mod 4)  (c is thread-private).
__global__ __launch_bounds__(256) void lstm_kernel(
    const float* __restrict__ seq, const float* __restrict__ WT,
    const float* __restrict__ attW, const float* __restrict__ attb,
    const float* __restrict__ outW, const float* __restrict__ outb,
    float* __restrict__ out, int N)
{
    __shared__ float xs[3][64][65];   // seq tiles (padded)
    __shared__ float hsd[64][97];     // shared hidden state (padded)
    __shared__ float logit[3][64];
    __shared__ float lpart[4][64];

    int tx = threadIdx.x & 63;
    int ty = threadIdx.x >> 6;
    int jty = __builtin_amdgcn_readfirstlane(ty);   // wave-uniform gate offset
    int n0 = blockIdx.x * 64;

    for (int idx = threadIdx.x; idx < 3 * 64 * 64; idx += 256) {
        int t = idx >> 12, r = (idx >> 6) & 63, k = idx & 63;
        int n = n0 + r;
        xs[t][r][k] = (n < N) ? seq[((size_t)t * N + n) * 64 + k] : 0.0f;
    }
    if (ty == 0) {
        float b0 = attb[0];
        logit[0][tx] = b0; logit[1][tx] = b0; logit[2][tx] = b0;
    }
    __syncthreads();

    for (int dir = 0; dir < 2; ++dir) {
        const float* base = WT + dir * 61824;
        const float* WihT = base;
        const float* WhhT = base + 24576;
        const float* bsum = base + 61440;
        const float* aw   = attW + dir * 96;

        float c[24];
        #pragma unroll
        for (int jj = 0; jj < 24; ++jj) c[jj] = 0.0f;
        for (int k = ty; k < 96; k += 4) hsd[tx][k] = 0.0f;
        __syncthreads();

        for (int step = 0; step < 3; ++step) {
            int t = dir ? (2 - step) : step;
            float g[96];
            #pragma unroll
            for (int uu = 0; uu < 96; ++uu) g[uu] = bsum[jty * 96 + uu];

            for (int k = 0; k < 64; ++k) {           // x @ Wih^T
                float xv = xs[t][tx][k];
                const float* wb = WihT + (k * 4 + jty) * 96;
                #pragma unroll
                for (int uu = 0; uu < 96; ++uu) g[uu] += xv * wb[uu];
            }
            for (int k = 0; k < 96; ++k) {           // h @ Whh^T
                float hv = hsd[tx][k];
                const float* wb = WhhT + (k * 4 + jty) * 96;
                #pragma unroll
                for (int uu = 0; uu < 96; ++uu) g[uu] += hv * wb[uu];
            }
            __syncthreads();                         // all reads of hsd done

            float lp = 0.0f;
            #pragma unroll
            for (int jj = 0; jj < 24; ++jj) {
                float ig = sigmoid_f(g[jj]);
                float fg = sigmoid_f(g[jj + 24]);
                float gg = tanh_f(g[jj + 48]);
                float og = sigmoid_f(g[jj + 72]);
                float cn = fg * c[jj] + ig * gg;
                c[jj] = cn;
                float hn = og * tanh_f(cn);
                int j = jty + 4 * jj;
                hsd[tx][j] = hn;
                lp += hn * aw[j];
            }
            lpart[ty][tx] = lp;
            __syncthreads();                         // hsd + lpart visible
            if (ty == 0)
                logit[t][tx] += lpart[0][tx] + lpart[1][tx]
                              + lpart[2][tx] + lpart[3][tx];
        }
        __syncthreads();
    }

    // alpha = softmax over the 3 layers
    if (ty == 0) {
        float l0 = logit[0][tx], l1 = logit[1][tx], l2 = logit[2][tx];
        float mx = fmaxf(fmaxf(l0, l1), l2);
        float e0 = __expf(l0 - mx), e1 = __expf(l1 - mx), e2 = __expf(l2 - mx);
        float inv = 1.0f / (e0 + e1 + e2);
        logit[0][tx] = e0 * inv; logit[1][tx] = e1 * inv; logit[2][tx] = e2 * inv;
    }
    __syncthreads();

    // agg[n][k] = sum_t alpha[t][n] * seq[t][n][k]  -> reuse hsd
    for (int idx = threadIdx.x; idx < 64 * 64; idx += 256) {
        int r = idx >> 6, k = idx & 63;
        hsd[r][k] = logit[0][r] * xs[0][r][k] + logit[1][r] * xs[1][r][k]
                  + logit[2][r] * xs[2][r][k];
    }
    __syncthreads();

    // stage outW into (now dead) xs[0] region
    float (*ow)[65] = reinterpret_cast<float(*)[65]>(&xs[0][0][0]);
    for (int idx = threadIdx.x; idx < 64 * 64; idx += 256)
        ow[idx >> 6][idx & 63] = outW[idx];
    __syncthreads();

    // out[n][j] = agg[n] . outW[j] + outb[j]   (lane = j, coalesced store)
    float ob = outb[tx];
    for (int r = ty; r < 64; r += 4) {
        int n = n0 + r;
        if (n >= N) break;
        float a = 0.0f;
        #pragma unroll
        for (int k = 0; k < 64; ++k) a += hsd[r][k] * ow[tx][k];
        out[(size_t)n * 64 + tx] = a + ob;
    }
}

// ---------------------------------------------------------------------------
extern "C" void kernel_launch(void* const* d_in, const int* in_sizes, int n_in,
                              void* d_out, int out_size, void* d_ws, size_t ws_size,
                              hipStream_t stream)
{
    const float* x    = (const float*)d_in[0];
    const int*   ei   = (const int*)d_in[1];
    const float* convW[3]  = {(const float*)d_in[2], (const float*)d_in[6],  (const float*)d_in[10]};
    const float* convAs[3] = {(const float*)d_in[3], (const float*)d_in[7],  (const float*)d_in[11]};
    const float* convAd[3] = {(const float*)d_in[4], (const float*)d_in[8],  (const float*)d_in[12]};
    const float* convB[3]  = {(const float*)d_in[5], (const float*)d_in[9],  (const float*)d_in[13]};
    const float* WihF = (const float*)d_in[14];
    const float* WhhF = (const float*)d_in[15];
    const float* bihF = (const float*)d_in[16];
    const float* bhhF = (const float*)d_in[17];
    const float* WihB = (const float*)d_in[18];
    const float* WhhB = (const float*)d_in[19];
    const float* bihB = (const float*)d_in[20];
    const float* bhhB = (const float*)d_in[21];
    const float* attW = (const float*)d_in[22];
    const float* attb = (const float*)d_in[23];
    const float* outW = (const float*)d_in[24];
    const float* outb = (const float*)d_in[25];

    int N = in_sizes[0] / 128;
    int E = in_sizes[1] / 2;
    const int* src = ei;
    const int* dst = ei + E;

    float* w = (float*)d_ws;
    float* seq  = w;  w += (size_t)3 * N * 64;
    float* h_ws = w;  w += (size_t)N * 64;
    float* acc  = w;  w += (size_t)N * 64;
    float* al   = w;  w += N;
    float* ar   = w;  w += N;
    float* mbuf = w;  w += N;
    float* den  = w;  w += N;
    float* e_ws = w;  w += (size_t)(E + N);
    float* WT   = w;  w += (size_t)2 * 61824;

    prep_lstm<<<(2 * 61824 + 255) / 256, 256, 0, stream>>>(
        WihF, WhhF, bihF, bhhF, WihB, WhhB, bihB, bhhB, WT);

    int nb_nodes = (N * 64 + 255) / 256;
    for (int l = 0; l < 3; ++l) {
        const float* in = (l == 0) ? x : seq + (size_t)(l - 1) * N * 64;
        if (l == 0)
            lin_kernel<128><<<2048, 256, 0, stream>>>(in, convW[l], convAs[l], convAd[l],
                                                      h_ws, al, ar, N);
        else
            lin_kernel<64><<<2048, 256, 0, stream>>>(in, convW[l], convAs[l], convAd[l],
                                                     h_ws, al, ar, N);
        init_layer<<<nb_nodes, 256, 0, stream>>>(mbuf, den, acc, N);
        edge1<<<(E + N + 255) / 256, 256, 0, stream>>>(src, dst, al, ar, e_ws, mbuf, E, N);
        edge2<<<16384, 256, 0, stream>>>(src, dst, e_ws, mbuf, h_ws, den, acc, E, N);
        finalize_kernel<<<nb_nodes, 256, 0, stream>>>(acc, den, convB[l],
                                                      seq + (size_t)l * N * 64, N);
    }

    lstm_kernel<<<(N + 63) / 64, 256, 0, stream>>>(seq, WT, attW, attb, outW, outb,
                                                   (float*)d_out, N);
}